// Round 7
// baseline (337.512 us; speedup 1.0000x reference)
//
#include <hip/hip_runtime.h>
#include <hip/hip_bf16.h>
#include <stdint.h>

#define N_NODES 50000
#define N_EDGES 800000
#define H_DIM 128
#define N_REL 40
#define N_BASES 4
#define A_COLS 640           // [hbf(128) | S(512)] unified per-node row
#define N_RANGES 196         // node ranges of 256 (dst >> 8)
#define N_CHUNKS 8           // edge chunks of 100000

typedef __attribute__((ext_vector_type(8))) short bf16x8;
typedef __attribute__((ext_vector_type(4))) float f32x4;

// round-to-nearest-even f32 -> bf16 bits
__device__ __forceinline__ unsigned short f2bf(float f) {
    unsigned int u = __float_as_uint(f);
    unsigned int r = u + 0x7fffu + ((u >> 16) & 1u);
    return (unsigned short)(r >> 16);
}

// ---------------------------------------------------------------------------
// K0 "prep": blocks 0..3124  -> cast h into A[:,0:128] (bf16) + dst histogram
//                              + pack per-edge payload pkd + range tag rtag
//            blocks 3125..3129 -> repack loop_w/basis_w into frag-major wt3
// pkd[e] = { src | etype<<20 ,  dst | nbf<<17 }  (nbf = bf16 bits of norm,
//           norm>=0 -> sign bit 0 -> nbf fits 15 bits; dst < 2^17)
// rtag[e] = dst >> 8  (0..195, fits u8)
__global__ __launch_bounds__(256) void prep_kernel(
        const float* __restrict__ h, const int* __restrict__ dst,
        const int* __restrict__ src, const int* __restrict__ etype,
        const float* __restrict__ norm,
        const float* __restrict__ basis_w, const float* __restrict__ loop_w,
        unsigned short* __restrict__ A, int* __restrict__ cnt,
        uint2* __restrict__ pkd, unsigned char* __restrict__ rtag,
        unsigned short* __restrict__ wt3) {
    int bid = blockIdx.x;
    if (bid < 3125) {
        int t = bid * 256 + threadIdx.x;        // [0, 800000)
        // cast: 8 elems of h per thread
        int row = t >> 4;
        int cb = (t & 15) * 8;
        const float* p = h + (size_t)row * 128 + cb;
        float4 a0 = ((const float4*)p)[0];
        float4 a1 = ((const float4*)p)[1];
        bf16x8 o;
        o[0] = (short)f2bf(a0.x); o[1] = (short)f2bf(a0.y);
        o[2] = (short)f2bf(a0.z); o[3] = (short)f2bf(a0.w);
        o[4] = (short)f2bf(a1.x); o[5] = (short)f2bf(a1.y);
        o[6] = (short)f2bf(a1.z); o[7] = (short)f2bf(a1.w);
        *(bf16x8*)(A + (size_t)row * A_COLS + cb) = o;
        // per-edge: histogram + payload pack + range tag
        int d = dst[t];
        unsigned int nbf = f2bf(norm[t]);       // <= 0x7FFF (norm >= 0)
        pkd[t] = make_uint2((unsigned)src[t] | ((unsigned)etype[t] << 20),
                            (unsigned)d | (nbf << 17));
        rtag[t] = (unsigned char)(d >> 8);
        atomicAdd(&cnt[d], 1);
    } else {
        int mat = bid - 3125;                   // 0..3 basis, 4 loop
        const float* srcm = (mat < 4) ? (basis_w + mat * 16384) : loop_w;
        int koff = (mat < 4) ? (128 + mat * 128) : 0;
        int t = threadIdx.x;
#pragma unroll
        for (int i = 0; i < 16; ++i) {
            int f = t + i * 256;                // [0,4096) float4 index
            int k = f >> 5;                     // source row (k within mat)
            int j4 = (f & 31) * 4;              // source col (j)
            float4 v = ((const float4*)srcm)[f];
            int kg = koff + k;
            int ks = kg >> 5;
            int quad = (kg >> 3) & 3;
            int jj = kg & 7;
            float vv[4] = {v.x, v.y, v.z, v.w};
#pragma unroll
            for (int d = 0; d < 4; ++d) {
                int j = j4 + d;
                int cg = j >> 4;
                int n16 = j & 15;
                wt3[(size_t)((ks * 8 + cg) * 64 + quad * 16 + n16) * 8 + jj] =
                    f2bf(vv[d]);
            }
        }
    }
}

// K1a: per-block (256-elem) exclusive scan; writes local scan + block sums.
__global__ __launch_bounds__(256) void scan_local(
        const int* __restrict__ cnt, int* __restrict__ offs,
        int* __restrict__ bsum) {
    __shared__ int wsum[4];
    int t = threadIdx.x, lane = t & 63, w = t >> 6;
    int i = blockIdx.x * 256 + t;
    int x = (i < N_NODES) ? cnt[i] : 0;
    int v = x;
#pragma unroll
    for (int d = 1; d < 64; d <<= 1) {
        int y = __shfl_up(v, d);
        if (lane >= d) v += y;
    }
    if (lane == 63) wsum[w] = v;
    __syncthreads();
    int wpre = 0;
    if (w > 0) wpre += wsum[0];
    if (w > 1) wpre += wsum[1];
    if (w > 2) wpre += wsum[2];
    if (i < N_NODES) offs[i] = wpre + v - x;
    if (t == 255) bsum[blockIdx.x] = wpre + v;
}

// K1b: scan the 196 block sums (single block); writes grand total.
__global__ __launch_bounds__(256) void scan_bsum(
        const int* __restrict__ bsum, int* __restrict__ bpre,
        int* __restrict__ offs) {
    __shared__ int wsum[4];
    int t = threadIdx.x, lane = t & 63, w = t >> 6;
    int x = (t < 196) ? bsum[t] : 0;
    int v = x;
#pragma unroll
    for (int d = 1; d < 64; d <<= 1) {
        int y = __shfl_up(v, d);
        if (lane >= d) v += y;
    }
    if (lane == 63) wsum[w] = v;
    __syncthreads();
    int wpre = 0;
    if (w > 0) wpre += wsum[0];
    if (w > 1) wpre += wsum[1];
    if (w > 2) wpre += wsum[2];
    if (t < 196) bpre[t] = wpre + v - x;
    if (t == 255) offs[N_NODES] = wpre + v;   // = N_EDGES
}

// K1c: add block prefixes; also initialize cursor.
__global__ __launch_bounds__(256) void scan_add(
        int* __restrict__ offs, const int* __restrict__ bpre,
        int* __restrict__ cursor) {
    int i = blockIdx.x * 256 + threadIdx.x;
    if (i < N_NODES) {
        int o = offs[i] + bpre[blockIdx.x];
        offs[i] = o;
        cursor[i] = o;
    }
}

// K2: partition-owned scatter. Block (range, chunk) scans its chunk's range
// tags (4 per u32, haszero test) and places only edges whose dst is in its
// 256-node range. All writes to one sorted_pe line come from <=2 XCDs within
// a short window -> lines are filled once, not ping-ponged.
// sorted_pe[pos] = { src | etype<<20 , f32 norm bits (from bf16) }
__global__ __launch_bounds__(256) void scatter_v2(
        const unsigned char* __restrict__ rtag,
        const uint2* __restrict__ pkd,
        int* __restrict__ cursor, uint2* __restrict__ sorted_pe) {
    int range = blockIdx.x % N_RANGES;
    int chunk = blockIdx.x / N_RANGES;          // 0..7
    int e0 = chunk * (N_EDGES / N_CHUNKS);      // chunk * 100000
    const unsigned int* rt4 = (const unsigned int*)(rtag + e0);
    unsigned int tgt4 = (unsigned)range * 0x01010101u;

    for (int i = threadIdx.x; i < (N_EDGES / N_CHUNKS) / 4; i += 256) {
        unsigned int x = rt4[i] ^ tgt4;         // zero byte where tag matches
        if (((x - 0x01010101u) & ~x & 0x80808080u) == 0) continue;
        int ebase = e0 + i * 4;
#pragma unroll
        for (int b = 0; b < 4; ++b) {
            if (((x >> (8 * b)) & 0xFFu) == 0u) {
                uint2 p = pkd[ebase + b];
                int d = p.y & 0x1FFFF;
                int pos = atomicAdd(&cursor[d], 1);
                sorted_pe[pos] = make_uint2(p.x, (p.y >> 17) << 16);
            }
        }
    }
}

// K3: per-node aggregation, no atomics. One wave per node; edge metadata is
// wave-uniform -> scalar loads; gather is one 256B row per edge (4B/lane).
// A[v][128 + b*128 + c] = sum_{e->v} cf[b] * A[src_e][c]   (bf16 out)
__global__ __launch_bounds__(256) void aggregate_kernel(
        const int* __restrict__ offs, const uint2* __restrict__ sorted_pe,
        const float* __restrict__ w_comp,
        unsigned short* __restrict__ A) {
    int v = __builtin_amdgcn_readfirstlane(blockIdx.x * 4 + (threadIdx.x >> 6));
    if (v >= N_NODES) return;
    int lane = threadIdx.x & 63;
    int begin = offs[v];
    int end = offs[v + 1];

    float a0l = 0.f, a0h = 0.f, a1l = 0.f, a1h = 0.f;
    float a2l = 0.f, a2h = 0.f, a3l = 0.f, a3h = 0.f;

    const unsigned int* Au = (const unsigned int*)A;

    int j = begin;
    for (; j + 4 <= end; j += 4) {
        uint2 p0 = sorted_pe[j + 0];
        uint2 p1 = sorted_pe[j + 1];
        uint2 p2 = sorted_pe[j + 2];
        uint2 p3 = sorted_pe[j + 3];
        int s0 = p0.x & 0xFFFFF;
        int s1 = p1.x & 0xFFFFF;
        int s2 = p2.x & 0xFFFFF;
        int s3 = p3.x & 0xFFFFF;
        unsigned int u0 = Au[(size_t)s0 * 320 + lane];
        unsigned int u1 = Au[(size_t)s1 * 320 + lane];
        unsigned int u2 = Au[(size_t)s2 * 320 + lane];
        unsigned int u3 = Au[(size_t)s3 * 320 + lane];

        float4 w0 = ((const float4*)w_comp)[p0.x >> 20];
        float4 w1 = ((const float4*)w_comp)[p1.x >> 20];
        float4 w2 = ((const float4*)w_comp)[p2.x >> 20];
        float4 w3 = ((const float4*)w_comp)[p3.x >> 20];
        float n0 = __uint_as_float(p0.y), n1 = __uint_as_float(p1.y);
        float n2 = __uint_as_float(p2.y), n3 = __uint_as_float(p3.y);

        float lo, hi;
        lo = __uint_as_float(u0 << 16); hi = __uint_as_float(u0 & 0xffff0000u);
        a0l += (w0.x * n0) * lo; a0h += (w0.x * n0) * hi;
        a1l += (w0.y * n0) * lo; a1h += (w0.y * n0) * hi;
        a2l += (w0.z * n0) * lo; a2h += (w0.z * n0) * hi;
        a3l += (w0.w * n0) * lo; a3h += (w0.w * n0) * hi;
        lo = __uint_as_float(u1 << 16); hi = __uint_as_float(u1 & 0xffff0000u);
        a0l += (w1.x * n1) * lo; a0h += (w1.x * n1) * hi;
        a1l += (w1.y * n1) * lo; a1h += (w1.y * n1) * hi;
        a2l += (w1.z * n1) * lo; a2h += (w1.z * n1) * hi;
        a3l += (w1.w * n1) * lo; a3h += (w1.w * n1) * hi;
        lo = __uint_as_float(u2 << 16); hi = __uint_as_float(u2 & 0xffff0000u);
        a0l += (w2.x * n2) * lo; a0h += (w2.x * n2) * hi;
        a1l += (w2.y * n2) * lo; a1h += (w2.y * n2) * hi;
        a2l += (w2.z * n2) * lo; a2h += (w2.z * n2) * hi;
        a3l += (w2.w * n2) * lo; a3h += (w2.w * n2) * hi;
        lo = __uint_as_float(u3 << 16); hi = __uint_as_float(u3 & 0xffff0000u);
        a0l += (w3.x * n3) * lo; a0h += (w3.x * n3) * hi;
        a1l += (w3.y * n3) * lo; a1h += (w3.y * n3) * hi;
        a2l += (w3.z * n3) * lo; a2h += (w3.z * n3) * hi;
        a3l += (w3.w * n3) * lo; a3h += (w3.w * n3) * hi;
    }
    for (; j < end; ++j) {
        uint2 p = sorted_pe[j];
        int s = p.x & 0xFFFFF;
        float4 wc = ((const float4*)w_comp)[p.x >> 20];
        float nm = __uint_as_float(p.y);
        unsigned int u = Au[(size_t)s * 320 + lane];
        float lo = __uint_as_float(u << 16);
        float hi = __uint_as_float(u & 0xffff0000u);
        a0l += (wc.x * nm) * lo; a0h += (wc.x * nm) * hi;
        a1l += (wc.y * nm) * lo; a1h += (wc.y * nm) * hi;
        a2l += (wc.z * nm) * lo; a2h += (wc.z * nm) * hi;
        a3l += (wc.w * nm) * lo; a3h += (wc.w * nm) * hi;
    }

    unsigned int* ps = (unsigned int*)(A + (size_t)v * A_COLS + 128);
    ps[0 * 64 + lane] = (unsigned int)f2bf(a0l) | ((unsigned int)f2bf(a0h) << 16);
    ps[1 * 64 + lane] = (unsigned int)f2bf(a1l) | ((unsigned int)f2bf(a1h) << 16);
    ps[2 * 64 + lane] = (unsigned int)f2bf(a2l) | ((unsigned int)f2bf(a2h) << 16);
    ps[3 * 64 + lane] = (unsigned int)f2bf(a3l) | ((unsigned int)f2bf(a3h) << 16);
}

// K4: out = relu(bias + A @ Wstack)   (M=50048, N=128, K=640 bf16 MFMA GEMM)
// Wave = 32 rows x 64 cols; block = 128 rows x 64 cols; grid (391, 2).
// 3128 waves (~12/CU). B frags are frag-major (contiguous 1 KB per load).
// Register double-buffer prefetch of next k-step's A+B frags.
__global__ __launch_bounds__(256, 4) void gemm_out(
        const unsigned short* __restrict__ A,
        const unsigned short* __restrict__ wt3,
        const float* __restrict__ bias,
        float* __restrict__ out) {
    int wv = threadIdx.x >> 6;
    int lane = threadIdx.x & 63;
    int n16 = lane & 15;
    int quad = lane >> 4;
    int r0 = (blockIdx.x * 4 + wv) * 32;
    int ch = blockIdx.y;            // column half (0/1)

    const unsigned short* ap0 = A + (size_t)(r0 + n16) * A_COLS + quad * 8;
    const unsigned short* ap1 = ap0 + 16 * A_COLS;
    // frag (ks, cg=ch*4+ct) base: wt3 + (ks*8+cg)*512 + lane*8
    const unsigned short* bp = wt3 + (size_t)(ch * 4) * 512 + (size_t)lane * 8;

    f32x4 acc[2][4];
#pragma unroll
    for (int rt = 0; rt < 2; ++rt)
#pragma unroll
        for (int ct = 0; ct < 4; ++ct)
            acc[rt][ct] = (f32x4)0.f;

    bf16x8 a_cur[2], b_cur[4];
    a_cur[0] = *(const bf16x8*)ap0;
    a_cur[1] = *(const bf16x8*)ap1;
#pragma unroll
    for (int ct = 0; ct < 4; ++ct)
        b_cur[ct] = *(const bf16x8*)(bp + ct * 512);

#pragma unroll
    for (int ks = 0; ks < 20; ++ks) {
        bf16x8 a_nxt[2], b_nxt[4];
        if (ks < 19) {
            a_nxt[0] = *(const bf16x8*)(ap0 + (ks + 1) * 32);
            a_nxt[1] = *(const bf16x8*)(ap1 + (ks + 1) * 32);
#pragma unroll
            for (int ct = 0; ct < 4; ++ct)
                b_nxt[ct] = *(const bf16x8*)(bp + (ks + 1) * 4096 + ct * 512);
        } else {
            a_nxt[0] = a_cur[0];
            a_nxt[1] = a_cur[1];
#pragma unroll
            for (int ct = 0; ct < 4; ++ct) b_nxt[ct] = b_cur[ct];
        }
#pragma unroll
        for (int ct = 0; ct < 4; ++ct) {
            acc[0][ct] = __builtin_amdgcn_mfma_f32_16x16x32_bf16(a_cur[0], b_cur[ct], acc[0][ct], 0, 0, 0);
            acc[1][ct] = __builtin_amdgcn_mfma_f32_16x16x32_bf16(a_cur[1], b_cur[ct], acc[1][ct], 0, 0, 0);
        }
        a_cur[0] = a_nxt[0];
        a_cur[1] = a_nxt[1];
#pragma unroll
        for (int ct = 0; ct < 4; ++ct) b_cur[ct] = b_nxt[ct];
    }

    // C/D layout: col = lane&15, row = quad*4 + reg
#pragma unroll
    for (int rt = 0; rt < 2; ++rt) {
        int rbase = r0 + rt * 16 + quad * 4;
#pragma unroll
        for (int ct = 0; ct < 4; ++ct) {
            int col = ch * 64 + ct * 16 + n16;
            float bv = bias[col];
#pragma unroll
            for (int rg = 0; rg < 4; ++rg) {
                int r = rbase + rg;
                if (r < N_NODES)
                    out[(size_t)r * H_DIM + col] = fmaxf(acc[rt][ct][rg] + bv, 0.f);
            }
        }
    }
}

extern "C" void kernel_launch(void* const* d_in, const int* in_sizes, int n_in,
                              void* d_out, int out_size, void* d_ws, size_t ws_size,
                              hipStream_t stream) {
    const float* h       = (const float*)d_in[0];
    const float* norm    = (const float*)d_in[1];
    const float* basis_w = (const float*)d_in[2];
    const float* w_comp  = (const float*)d_in[3];
    const float* loop_w  = (const float*)d_in[4];
    const float* bias    = (const float*)d_in[5];
    const int*   src     = (const int*)d_in[6];
    const int*   dst     = (const int*)d_in[7];
    const int*   etype   = (const int*)d_in[8];
    float* out = (float*)d_out;

    // ws layout (bytes):
    char* base = (char*)d_ws;
    unsigned short* wt3        = (unsigned short*)(base + 0);          //    163,840
    unsigned short* A          = (unsigned short*)(base + 163840);     // 64,061,440
    int*            cnt        = (int*)(base + 64225280);              //    200,000
    int*            offs       = (int*)(base + 64425280);              //    200,064
    int*            cursor     = (int*)(base + 64625344);              //    200,000
    uint2*          sorted_pe  = (uint2*)(base + 64825344);            //  6,400,000
    int*            bsum       = (int*)(base + 71225344);              //        784
    int*            bpre       = (int*)(base + 71226128);              //        784
    uint2*          pkd        = (uint2*)(base + 71226912);            //  6,400,000
    unsigned char*  rtag       = (unsigned char*)(base + 77626912);    //    800,000
    // total ~78.4 MB

    hipMemsetAsync(cnt, 0, N_NODES * sizeof(int), stream);
    prep_kernel<<<3130, 256, 0, stream>>>(h, dst, src, etype, norm,
                                          basis_w, loop_w, A, cnt, pkd, rtag, wt3);
    scan_local<<<196, 256, 0, stream>>>(cnt, offs, bsum);
    scan_bsum<<<1, 256, 0, stream>>>(bsum, bpre, offs);
    scan_add<<<196, 256, 0, stream>>>(offs, bpre, cursor);
    scatter_v2<<<N_RANGES * N_CHUNKS, 256, 0, stream>>>(rtag, pkd, cursor, sorted_pe);
    aggregate_kernel<<<12500, 256, 0, stream>>>(offs, sorted_pe, w_comp, A);
    gemm_out<<<dim3(391, 2), 256, 0, stream>>>(A, wt3, bias, out);
}

// Round 8
// 254.253 us; speedup vs baseline: 1.3275x; 1.3275x over previous
//
#include <hip/hip_runtime.h>
#include <hip/hip_bf16.h>
#include <stdint.h>

#define N_NODES 50000
#define N_EDGES 800000
#define H_DIM 128
#define N_REL 40
#define N_BASES 4
#define A_COLS 640           // [hbf(128) | S(512)] unified per-node row
#define N_RANGES 196         // node ranges of 256 (dst >> 8)
#define EP_BLOCKS 200        // edge chunks of 4000
#define EDGES_PER_BLK 4000

typedef __attribute__((ext_vector_type(8))) short bf16x8;
typedef __attribute__((ext_vector_type(4))) float f32x4;

// round-to-nearest-even f32 -> bf16 bits
__device__ __forceinline__ unsigned short f2bf(float f) {
    unsigned int u = __float_as_uint(f);
    unsigned int r = u + 0x7fffu + ((u >> 16) & 1u);
    return (unsigned short)(r >> 16);
}

// ---------------------------------------------------------------------------
// K0 "prep": blocks 0..3124  -> cast h into A[:,0:128] (bf16)
//            blocks 3125..3129 -> repack loop_w/basis_w into frag-major wt3
__global__ __launch_bounds__(256) void prep_kernel(
        const float* __restrict__ h,
        const float* __restrict__ basis_w, const float* __restrict__ loop_w,
        unsigned short* __restrict__ A, unsigned short* __restrict__ wt3) {
    int bid = blockIdx.x;
    if (bid < 3125) {
        int t = bid * 256 + threadIdx.x;        // [0, 800000)
        int row = t >> 4;
        int cb = (t & 15) * 8;
        const float* p = h + (size_t)row * 128 + cb;
        float4 a0 = ((const float4*)p)[0];
        float4 a1 = ((const float4*)p)[1];
        bf16x8 o;
        o[0] = (short)f2bf(a0.x); o[1] = (short)f2bf(a0.y);
        o[2] = (short)f2bf(a0.z); o[3] = (short)f2bf(a0.w);
        o[4] = (short)f2bf(a1.x); o[5] = (short)f2bf(a1.y);
        o[6] = (short)f2bf(a1.z); o[7] = (short)f2bf(a1.w);
        *(bf16x8*)(A + (size_t)row * A_COLS + cb) = o;
    } else {
        int mat = bid - 3125;                   // 0..3 basis, 4 loop
        const float* srcm = (mat < 4) ? (basis_w + mat * 16384) : loop_w;
        int koff = (mat < 4) ? (128 + mat * 128) : 0;
        int t = threadIdx.x;
#pragma unroll
        for (int i = 0; i < 16; ++i) {
            int f = t + i * 256;                // [0,4096) float4 index
            int k = f >> 5;
            int j4 = (f & 31) * 4;
            float4 v = ((const float4*)srcm)[f];
            int kg = koff + k;
            int ks = kg >> 5;
            int quad = (kg >> 3) & 3;
            int jj = kg & 7;
            float vv[4] = {v.x, v.y, v.z, v.w};
#pragma unroll
            for (int d = 0; d < 4; ++d) {
                int j = j4 + d;
                int cg = j >> 4;
                int n16 = j & 15;
                wt3[(size_t)((ks * 8 + cg) * 64 + quad * 16 + n16) * 8 + jj] =
                    f2bf(vv[d]);
            }
        }
    }
}

// K0b "edge_prep": one pass over edge arrays. Packs pkd, global per-dst
// histogram (cnt), and per-(bucket, block) histogram gcnt[r*200+b].
// pkd[e] = { src | etype<<20 , dst | nbf<<17 }   (nbf = bf16 of norm >= 0)
__global__ __launch_bounds__(256) void edge_prep(
        const int* __restrict__ src, const int* __restrict__ dst,
        const int* __restrict__ etype, const float* __restrict__ norm,
        uint2* __restrict__ pkd, int* __restrict__ cnt,
        int* __restrict__ gcnt) {
    __shared__ int lhist[N_RANGES];
    int t = threadIdx.x;
    if (t < N_RANGES) lhist[t] = 0;
    __syncthreads();
    int e0 = blockIdx.x * EDGES_PER_BLK;
    for (int i = t; i < EDGES_PER_BLK; i += 256) {
        int e = e0 + i;
        int d = dst[e];
        unsigned int nbf = f2bf(norm[e]);       // <= 0x7FFF
        pkd[e] = make_uint2((unsigned)src[e] | ((unsigned)etype[e] << 20),
                            (unsigned)d | (nbf << 17));
        atomicAdd(&cnt[d], 1);
        atomicAdd(&lhist[d >> 8], 1);
    }
    __syncthreads();
    if (t < N_RANGES) gcnt[t * EP_BLOCKS + blockIdx.x] = lhist[t];
}

// K1a: per-block (256-elem) exclusive scan; writes local scan + block sums.
__global__ __launch_bounds__(256) void scan_local(
        const int* __restrict__ cnt, int* __restrict__ offs,
        int* __restrict__ bsum) {
    __shared__ int wsum[4];
    int t = threadIdx.x, lane = t & 63, w = t >> 6;
    int i = blockIdx.x * 256 + t;
    int x = (i < N_NODES) ? cnt[i] : 0;
    int v = x;
#pragma unroll
    for (int d = 1; d < 64; d <<= 1) {
        int y = __shfl_up(v, d);
        if (lane >= d) v += y;
    }
    if (lane == 63) wsum[w] = v;
    __syncthreads();
    int wpre = 0;
    if (w > 0) wpre += wsum[0];
    if (w > 1) wpre += wsum[1];
    if (w > 2) wpre += wsum[2];
    if (i < N_NODES) offs[i] = wpre + v - x;
    if (t == 255) bsum[blockIdx.x] = wpre + v;
}

// K1b: scan the 196 block sums (single block); writes grand total.
__global__ __launch_bounds__(256) void scan_bsum(
        const int* __restrict__ bsum, int* __restrict__ bpre,
        int* __restrict__ offs) {
    __shared__ int wsum[4];
    int t = threadIdx.x, lane = t & 63, w = t >> 6;
    int x = (t < 196) ? bsum[t] : 0;
    int v = x;
#pragma unroll
    for (int d = 1; d < 64; d <<= 1) {
        int y = __shfl_up(v, d);
        if (lane >= d) v += y;
    }
    if (lane == 63) wsum[w] = v;
    __syncthreads();
    int wpre = 0;
    if (w > 0) wpre += wsum[0];
    if (w > 1) wpre += wsum[1];
    if (w > 2) wpre += wsum[2];
    if (t < 196) bpre[t] = wpre + v - x;
    if (t == 255) offs[N_NODES] = wpre + v;   // = N_EDGES
}

// K1c: add block prefixes.
__global__ __launch_bounds__(256) void scan_add(
        int* __restrict__ offs, const int* __restrict__ bpre) {
    int i = blockIdx.x * 256 + threadIdx.x;
    if (i < N_NODES) offs[i] = offs[i] + bpre[blockIdx.x];
}

// K2a: per-(bucket,block) bases. blkbase[r][b] = offs[r*256] + prefix of
// gcnt[r][0..b). Bucket regions start at offs[r*256] because sort-by-dst is
// bucket-contiguous. Single block, thread r owns bucket r.
__global__ __launch_bounds__(256) void scan2(
        const int* __restrict__ offs, const int* __restrict__ gcnt,
        int* __restrict__ blkbase) {
    int r = threadIdx.x;
    if (r >= N_RANGES) return;
    int base = offs[r * 256];
    for (int b = 0; b < EP_BLOCKS; ++b) {
        int idx = r * EP_BLOCKS + b;
        int c = gcnt[idx];
        blkbase[idx] = base;
        base += c;
    }
}

// K2b: binscatter. Block b places its 4000 edges into bucket-grouped order.
// Each (block,bucket) chunk (~20 edges, 160 B) is contiguous and written by
// exactly one block -> near-1x write amplification.
__global__ __launch_bounds__(256) void binscatter(
        const uint2* __restrict__ pkd, const int* __restrict__ blkbase,
        uint2* __restrict__ bucketed) {
    __shared__ int lcur[N_RANGES];
    int t = threadIdx.x;
    if (t < N_RANGES) lcur[t] = blkbase[t * EP_BLOCKS + blockIdx.x];
    __syncthreads();
    int e0 = blockIdx.x * EDGES_PER_BLK;
    for (int i = t; i < EDGES_PER_BLK; i += 256) {
        uint2 p = pkd[e0 + i];
        int r = (p.y & 0x1FFFF) >> 8;
        int pos = atomicAdd(&lcur[r], 1);
        bucketed[pos] = p;
    }
}

// K2c: bucket_sort. One block per bucket; reads its region coalesced, LDS
// per-dst cursors, writes exact dst-sorted order. The output region
// (~32 KB) has a SINGLE writer block -> lines written back once.
// sorted_pe[pos] = { src | etype<<20 , f32 norm bits }
__global__ __launch_bounds__(256) void bucket_sort(
        const int* __restrict__ offs, const uint2* __restrict__ bucketed,
        uint2* __restrict__ sorted_pe) {
    __shared__ int cur[256];
    int r = blockIdx.x;
    int t = threadIdx.x;
    int node = r * 256 + t;
    cur[t] = (node < N_NODES) ? offs[node] : N_EDGES;
    __syncthreads();
    int begin = offs[r * 256];
    int endn = (r + 1) * 256; if (endn > N_NODES) endn = N_NODES;
    int end = offs[endn];
    for (int i = begin + t; i < end; i += 256) {
        uint2 p = bucketed[i];
        int d = p.y & 0x1FFFF;
        int pos = atomicAdd(&cur[d & 255], 1);
        sorted_pe[pos] = make_uint2(p.x, (p.y >> 17) << 16);
    }
}

// K3: per-node aggregation, no atomics. One wave per node; edge metadata is
// wave-uniform -> scalar loads; gather is one 256B row per edge (4B/lane).
// A[v][128 + b*128 + c] = sum_{e->v} cf[b] * A[src_e][c]   (bf16 out)
__global__ __launch_bounds__(256) void aggregate_kernel(
        const int* __restrict__ offs, const uint2* __restrict__ sorted_pe,
        const float* __restrict__ w_comp,
        unsigned short* __restrict__ A) {
    int v = __builtin_amdgcn_readfirstlane(blockIdx.x * 4 + (threadIdx.x >> 6));
    if (v >= N_NODES) return;
    int lane = threadIdx.x & 63;
    int begin = offs[v];
    int end = offs[v + 1];

    float a0l = 0.f, a0h = 0.f, a1l = 0.f, a1h = 0.f;
    float a2l = 0.f, a2h = 0.f, a3l = 0.f, a3h = 0.f;

    const unsigned int* Au = (const unsigned int*)A;

    int j = begin;
    for (; j + 4 <= end; j += 4) {
        uint2 p0 = sorted_pe[j + 0];
        uint2 p1 = sorted_pe[j + 1];
        uint2 p2 = sorted_pe[j + 2];
        uint2 p3 = sorted_pe[j + 3];
        int s0 = p0.x & 0xFFFFF;
        int s1 = p1.x & 0xFFFFF;
        int s2 = p2.x & 0xFFFFF;
        int s3 = p3.x & 0xFFFFF;
        unsigned int u0 = Au[(size_t)s0 * 320 + lane];
        unsigned int u1 = Au[(size_t)s1 * 320 + lane];
        unsigned int u2 = Au[(size_t)s2 * 320 + lane];
        unsigned int u3 = Au[(size_t)s3 * 320 + lane];

        float4 w0 = ((const float4*)w_comp)[p0.x >> 20];
        float4 w1 = ((const float4*)w_comp)[p1.x >> 20];
        float4 w2 = ((const float4*)w_comp)[p2.x >> 20];
        float4 w3 = ((const float4*)w_comp)[p3.x >> 20];
        float n0 = __uint_as_float(p0.y), n1 = __uint_as_float(p1.y);
        float n2 = __uint_as_float(p2.y), n3 = __uint_as_float(p3.y);

        float lo, hi;
        lo = __uint_as_float(u0 << 16); hi = __uint_as_float(u0 & 0xffff0000u);
        a0l += (w0.x * n0) * lo; a0h += (w0.x * n0) * hi;
        a1l += (w0.y * n0) * lo; a1h += (w0.y * n0) * hi;
        a2l += (w0.z * n0) * lo; a2h += (w0.z * n0) * hi;
        a3l += (w0.w * n0) * lo; a3h += (w0.w * n0) * hi;
        lo = __uint_as_float(u1 << 16); hi = __uint_as_float(u1 & 0xffff0000u);
        a0l += (w1.x * n1) * lo; a0h += (w1.x * n1) * hi;
        a1l += (w1.y * n1) * lo; a1h += (w1.y * n1) * hi;
        a2l += (w1.z * n1) * lo; a2h += (w1.z * n1) * hi;
        a3l += (w1.w * n1) * lo; a3h += (w1.w * n1) * hi;
        lo = __uint_as_float(u2 << 16); hi = __uint_as_float(u2 & 0xffff0000u);
        a0l += (w2.x * n2) * lo; a0h += (w2.x * n2) * hi;
        a1l += (w2.y * n2) * lo; a1h += (w2.y * n2) * hi;
        a2l += (w2.z * n2) * lo; a2h += (w2.z * n2) * hi;
        a3l += (w2.w * n2) * lo; a3h += (w2.w * n2) * hi;
        lo = __uint_as_float(u3 << 16); hi = __uint_as_float(u3 & 0xffff0000u);
        a0l += (w3.x * n3) * lo; a0h += (w3.x * n3) * hi;
        a1l += (w3.y * n3) * lo; a1h += (w3.y * n3) * hi;
        a2l += (w3.z * n3) * lo; a2h += (w3.z * n3) * hi;
        a3l += (w3.w * n3) * lo; a3h += (w3.w * n3) * hi;
    }
    for (; j < end; ++j) {
        uint2 p = sorted_pe[j];
        int s = p.x & 0xFFFFF;
        float4 wc = ((const float4*)w_comp)[p.x >> 20];
        float nm = __uint_as_float(p.y);
        unsigned int u = Au[(size_t)s * 320 + lane];
        float lo = __uint_as_float(u << 16);
        float hi = __uint_as_float(u & 0xffff0000u);
        a0l += (wc.x * nm) * lo; a0h += (wc.x * nm) * hi;
        a1l += (wc.y * nm) * lo; a1h += (wc.y * nm) * hi;
        a2l += (wc.z * nm) * lo; a2h += (wc.z * nm) * hi;
        a3l += (wc.w * nm) * lo; a3h += (wc.w * nm) * hi;
    }

    unsigned int* ps = (unsigned int*)(A + (size_t)v * A_COLS + 128);
    ps[0 * 64 + lane] = (unsigned int)f2bf(a0l) | ((unsigned int)f2bf(a0h) << 16);
    ps[1 * 64 + lane] = (unsigned int)f2bf(a1l) | ((unsigned int)f2bf(a1h) << 16);
    ps[2 * 64 + lane] = (unsigned int)f2bf(a2l) | ((unsigned int)f2bf(a2h) << 16);
    ps[3 * 64 + lane] = (unsigned int)f2bf(a3l) | ((unsigned int)f2bf(a3h) << 16);
}

// K4: out = relu(bias + A @ Wstack)   (M=50048, N=128, K=640 bf16 MFMA GEMM)
// Wave = 32 rows x 64 cols; block = 128 rows x 64 cols; grid (391, 2).
__global__ __launch_bounds__(256, 4) void gemm_out(
        const unsigned short* __restrict__ A,
        const unsigned short* __restrict__ wt3,
        const float* __restrict__ bias,
        float* __restrict__ out) {
    int wv = threadIdx.x >> 6;
    int lane = threadIdx.x & 63;
    int n16 = lane & 15;
    int quad = lane >> 4;
    int r0 = (blockIdx.x * 4 + wv) * 32;
    int ch = blockIdx.y;            // column half (0/1)

    const unsigned short* ap0 = A + (size_t)(r0 + n16) * A_COLS + quad * 8;
    const unsigned short* ap1 = ap0 + 16 * A_COLS;
    const unsigned short* bp = wt3 + (size_t)(ch * 4) * 512 + (size_t)lane * 8;

    f32x4 acc[2][4];
#pragma unroll
    for (int rt = 0; rt < 2; ++rt)
#pragma unroll
        for (int ct = 0; ct < 4; ++ct)
            acc[rt][ct] = (f32x4)0.f;

    bf16x8 a_cur[2], b_cur[4];
    a_cur[0] = *(const bf16x8*)ap0;
    a_cur[1] = *(const bf16x8*)ap1;
#pragma unroll
    for (int ct = 0; ct < 4; ++ct)
        b_cur[ct] = *(const bf16x8*)(bp + ct * 512);

#pragma unroll
    for (int ks = 0; ks < 20; ++ks) {
        bf16x8 a_nxt[2], b_nxt[4];
        if (ks < 19) {
            a_nxt[0] = *(const bf16x8*)(ap0 + (ks + 1) * 32);
            a_nxt[1] = *(const bf16x8*)(ap1 + (ks + 1) * 32);
#pragma unroll
            for (int ct = 0; ct < 4; ++ct)
                b_nxt[ct] = *(const bf16x8*)(bp + (ks + 1) * 4096 + ct * 512);
        } else {
            a_nxt[0] = a_cur[0];
            a_nxt[1] = a_cur[1];
#pragma unroll
            for (int ct = 0; ct < 4; ++ct) b_nxt[ct] = b_cur[ct];
        }
#pragma unroll
        for (int ct = 0; ct < 4; ++ct) {
            acc[0][ct] = __builtin_amdgcn_mfma_f32_16x16x32_bf16(a_cur[0], b_cur[ct], acc[0][ct], 0, 0, 0);
            acc[1][ct] = __builtin_amdgcn_mfma_f32_16x16x32_bf16(a_cur[1], b_cur[ct], acc[1][ct], 0, 0, 0);
        }
        a_cur[0] = a_nxt[0];
        a_cur[1] = a_nxt[1];
#pragma unroll
        for (int ct = 0; ct < 4; ++ct) b_cur[ct] = b_nxt[ct];
    }

    // C/D layout: col = lane&15, row = quad*4 + reg
#pragma unroll
    for (int rt = 0; rt < 2; ++rt) {
        int rbase = r0 + rt * 16 + quad * 4;
#pragma unroll
        for (int ct = 0; ct < 4; ++ct) {
            int col = ch * 64 + ct * 16 + n16;
            float bv = bias[col];
#pragma unroll
            for (int rg = 0; rg < 4; ++rg) {
                int r = rbase + rg;
                if (r < N_NODES)
                    out[(size_t)r * H_DIM + col] = fmaxf(acc[rt][ct][rg] + bv, 0.f);
            }
        }
    }
}

extern "C" void kernel_launch(void* const* d_in, const int* in_sizes, int n_in,
                              void* d_out, int out_size, void* d_ws, size_t ws_size,
                              hipStream_t stream) {
    const float* h       = (const float*)d_in[0];
    const float* norm    = (const float*)d_in[1];
    const float* basis_w = (const float*)d_in[2];
    const float* w_comp  = (const float*)d_in[3];
    const float* loop_w  = (const float*)d_in[4];
    const float* bias    = (const float*)d_in[5];
    const int*   src     = (const int*)d_in[6];
    const int*   dst     = (const int*)d_in[7];
    const int*   etype   = (const int*)d_in[8];
    float* out = (float*)d_out;

    // ws layout (bytes):
    char* base = (char*)d_ws;
    unsigned short* wt3       = (unsigned short*)(base + 0);          //    163,840
    unsigned short* A         = (unsigned short*)(base + 163840);     // 64,061,440
    int*            cnt       = (int*)(base + 64225280);              //    200,000
    int*            offs      = (int*)(base + 64425280);              //    200,064
    uint2*          pkd       = (uint2*)(base + 64625344);            //  6,400,000
    uint2*          bucketed  = (uint2*)(base + 71025344);            //  6,400,000
    uint2*          sorted_pe = (uint2*)(base + 77425344);            //  6,400,000
    int*            gcnt      = (int*)(base + 83825344);              //    156,800
    int*            blkbase   = (int*)(base + 83982144);              //    156,800
    int*            bsum      = (int*)(base + 84138944);              //        784
    int*            bpre      = (int*)(base + 84139728);              //        784
    // total ~84.1 MB

    hipMemsetAsync(cnt, 0, N_NODES * sizeof(int), stream);
    prep_kernel<<<3130, 256, 0, stream>>>(h, basis_w, loop_w, A, wt3);
    edge_prep<<<EP_BLOCKS, 256, 0, stream>>>(src, dst, etype, norm,
                                             pkd, cnt, gcnt);
    scan_local<<<196, 256, 0, stream>>>(cnt, offs, bsum);
    scan_bsum<<<1, 256, 0, stream>>>(bsum, bpre, offs);
    scan_add<<<196, 256, 0, stream>>>(offs, bpre);
    scan2<<<1, 256, 0, stream>>>(offs, gcnt, blkbase);
    binscatter<<<EP_BLOCKS, 256, 0, stream>>>(pkd, blkbase, bucketed);
    bucket_sort<<<N_RANGES, 256, 0, stream>>>(offs, bucketed, sorted_pe);
    aggregate_kernel<<<12500, 256, 0, stream>>>(offs, sorted_pe, w_comp, A);
    gemm_out<<<dim3(391, 2), 256, 0, stream>>>(A, wt3, bias, out);
}

// Round 9
// 216.631 us; speedup vs baseline: 1.5580x; 1.1737x over previous
//
#include <hip/hip_runtime.h>
#include <hip/hip_bf16.h>
#include <stdint.h>

#define N_NODES 50000
#define N_EDGES 800000
#define H_DIM 128
#define N_REL 40
#define N_BASES 4
#define A_COLS 640           // [hbf(128) | S(512)] unified per-node row
#define N_RANGES 196         // node ranges of 256 (dst >> 8)
#define EP_BLOCKS 200        // edge chunks of 4000
#define EDGES_PER_BLK 4000

typedef __attribute__((ext_vector_type(8))) short bf16x8;
typedef __attribute__((ext_vector_type(4))) float f32x4;

// round-to-nearest-even f32 -> bf16 bits
__device__ __forceinline__ unsigned short f2bf(float f) {
    unsigned int u = __float_as_uint(f);
    unsigned int r = u + 0x7fffu + ((u >> 16) & 1u);
    return (unsigned short)(r >> 16);
}

// ---------------------------------------------------------------------------
// K0 "prep": blocks 0..3124  -> cast h into A[:,0:128] (bf16)
//            blocks 3125..3129 -> repack loop_w/basis_w into frag-major wt3
__global__ __launch_bounds__(256) void prep_kernel(
        const float* __restrict__ h,
        const float* __restrict__ basis_w, const float* __restrict__ loop_w,
        unsigned short* __restrict__ A, unsigned short* __restrict__ wt3) {
    int bid = blockIdx.x;
    if (bid < 3125) {
        int t = bid * 256 + threadIdx.x;        // [0, 800000)
        int row = t >> 4;
        int cb = (t & 15) * 8;
        const float* p = h + (size_t)row * 128 + cb;
        float4 a0 = ((const float4*)p)[0];
        float4 a1 = ((const float4*)p)[1];
        bf16x8 o;
        o[0] = (short)f2bf(a0.x); o[1] = (short)f2bf(a0.y);
        o[2] = (short)f2bf(a0.z); o[3] = (short)f2bf(a0.w);
        o[4] = (short)f2bf(a1.x); o[5] = (short)f2bf(a1.y);
        o[6] = (short)f2bf(a1.z); o[7] = (short)f2bf(a1.w);
        *(bf16x8*)(A + (size_t)row * A_COLS + cb) = o;
    } else {
        int mat = bid - 3125;                   // 0..3 basis, 4 loop
        const float* srcm = (mat < 4) ? (basis_w + mat * 16384) : loop_w;
        int koff = (mat < 4) ? (128 + mat * 128) : 0;
        int t = threadIdx.x;
#pragma unroll
        for (int i = 0; i < 16; ++i) {
            int f = t + i * 256;                // [0,4096) float4 index
            int k = f >> 5;
            int j4 = (f & 31) * 4;
            float4 v = ((const float4*)srcm)[f];
            int kg = koff + k;
            int ks = kg >> 5;
            int quad = (kg >> 3) & 3;
            int jj = kg & 7;
            float vv[4] = {v.x, v.y, v.z, v.w};
#pragma unroll
            for (int d = 0; d < 4; ++d) {
                int j = j4 + d;
                int cg = j >> 4;
                int n16 = j & 15;
                wt3[(size_t)((ks * 8 + cg) * 64 + quad * 16 + n16) * 8 + jj] =
                    f2bf(vv[d]);
            }
        }
    }
}

// K0b "edge_prep": pack pkd + per-(bucket, block) histogram (LDS only, no
// device atomics). pkd[e] = { src | etype<<20 , dst | nbf<<17 }.
__global__ __launch_bounds__(256) void edge_prep(
        const int* __restrict__ src, const int* __restrict__ dst,
        const int* __restrict__ etype, const float* __restrict__ norm,
        uint2* __restrict__ pkd, int* __restrict__ gcnt) {
    __shared__ int lhist[N_RANGES];
    int t = threadIdx.x;
    if (t < N_RANGES) lhist[t] = 0;
    __syncthreads();
    int e0 = blockIdx.x * EDGES_PER_BLK;
    for (int i = t; i < EDGES_PER_BLK; i += 256) {
        int e = e0 + i;
        int d = dst[e];
        unsigned int nbf = f2bf(norm[e]);       // <= 0x7FFF (norm >= 0)
        pkd[e] = make_uint2((unsigned)src[e] | ((unsigned)etype[e] << 20),
                            (unsigned)d | (nbf << 17));
        atomicAdd(&lhist[d >> 8], 1);
    }
    __syncthreads();
    if (t < N_RANGES) gcnt[t * EP_BLOCKS + blockIdx.x] = lhist[t];
}

// K1: single block. Thread r: (a) sum gcnt row -> bucket total, (b) shfl
// exclusive scan across 196 buckets -> bstart, (c) walk row emitting blkbase.
__global__ __launch_bounds__(256) void bucket_scan(
        const int* __restrict__ gcnt, int* __restrict__ blkbase,
        int* __restrict__ bstart, int* __restrict__ offs) {
    __shared__ int wsum[4];
    int t = threadIdx.x, lane = t & 63, w = t >> 6;
    int tot = 0;
    if (t < N_RANGES) {
        const int* row = gcnt + t * EP_BLOCKS;
#pragma unroll 8
        for (int b = 0; b < EP_BLOCKS; ++b) tot += row[b];
    }
    int v = tot;
#pragma unroll
    for (int d = 1; d < 64; d <<= 1) {
        int y = __shfl_up(v, d);
        if (lane >= d) v += y;
    }
    if (lane == 63) wsum[w] = v;
    __syncthreads();
    int wpre = 0;
    if (w > 0) wpre += wsum[0];
    if (w > 1) wpre += wsum[1];
    if (w > 2) wpre += wsum[2];
    int excl = wpre + v - tot;
    if (t < N_RANGES) bstart[t] = excl;
    if (t == N_RANGES - 1) {
        bstart[N_RANGES] = wpre + v;            // = N_EDGES
        offs[N_NODES] = wpre + v;
    }
    if (t < N_RANGES) {
        int base = excl;
        const int* row = gcnt + t * EP_BLOCKS;
        int* brow = blkbase + t * EP_BLOCKS;
        for (int b = 0; b < EP_BLOCKS; ++b) { brow[b] = base; base += row[b]; }
    }
}

// K2: binscatter. Block b places its 4000 edges into bucket-grouped order.
// Each (block,bucket) chunk (~20 edges, 160 B) is contiguous -> ~1x write amp.
__global__ __launch_bounds__(256) void binscatter(
        const uint2* __restrict__ pkd, const int* __restrict__ blkbase,
        uint2* __restrict__ bucketed) {
    __shared__ int lcur[N_RANGES];
    int t = threadIdx.x;
    if (t < N_RANGES) lcur[t] = blkbase[t * EP_BLOCKS + blockIdx.x];
    __syncthreads();
    int e0 = blockIdx.x * EDGES_PER_BLK;
    for (int i = t; i < EDGES_PER_BLK; i += 256) {
        uint2 p = pkd[e0 + i];
        int r = (p.y & 0x1FFFF) >> 8;
        int pos = atomicAdd(&lcur[r], 1);
        bucketed[pos] = p;
    }
}

// K3: bucket_sort. One block per bucket. Pass 1: LDS per-dst histogram of
// its region. LDS 256-wide exclusive scan -> per-dst offsets; writes
// offs[node] coalesced. Pass 2: place edges via LDS cursors. Output region
// has a SINGLE writer block -> lines written back once.
__global__ __launch_bounds__(256) void bucket_sort(
        const int* __restrict__ bstart, const uint2* __restrict__ bucketed,
        uint2* __restrict__ sorted_pe, int* __restrict__ offs) {
    __shared__ int hist[256];
    __shared__ int cur[256];
    __shared__ int wsum[4];
    int r = blockIdx.x;
    int t = threadIdx.x, lane = t & 63, w = t >> 6;
    int begin = bstart[r];
    int end = bstart[r + 1];
    hist[t] = 0;
    __syncthreads();
    for (int i = begin + t; i < end; i += 256)
        atomicAdd(&hist[bucketed[i].y & 255], 1);
    __syncthreads();
    int x = hist[t];
    int v = x;
#pragma unroll
    for (int d = 1; d < 64; d <<= 1) {
        int y = __shfl_up(v, d);
        if (lane >= d) v += y;
    }
    if (lane == 63) wsum[w] = v;
    __syncthreads();
    int wpre = 0;
    if (w > 0) wpre += wsum[0];
    if (w > 1) wpre += wsum[1];
    if (w > 2) wpre += wsum[2];
    int excl = begin + wpre + v - x;
    int node = r * 256 + t;
    if (node < N_NODES) offs[node] = excl;
    cur[t] = excl;
    __syncthreads();
    for (int i = begin + t; i < end; i += 256) {
        uint2 p = bucketed[i];
        int pos = atomicAdd(&cur[p.y & 255], 1);
        sorted_pe[pos] = make_uint2(p.x, (p.y >> 17) << 16);
    }
}

// K4: per-node aggregation, no atomics. One wave per node; edge metadata is
// wave-uniform -> scalar loads; gather is one 256B row per edge (4B/lane).
// A[v][128 + b*128 + c] = sum_{e->v} cf[b] * A[src_e][c]   (bf16 out)
__global__ __launch_bounds__(256) void aggregate_kernel(
        const int* __restrict__ offs, const uint2* __restrict__ sorted_pe,
        const float* __restrict__ w_comp,
        unsigned short* __restrict__ A) {
    int v = __builtin_amdgcn_readfirstlane(blockIdx.x * 4 + (threadIdx.x >> 6));
    if (v >= N_NODES) return;
    int lane = threadIdx.x & 63;
    int begin = offs[v];
    int end = offs[v + 1];

    float a0l = 0.f, a0h = 0.f, a1l = 0.f, a1h = 0.f;
    float a2l = 0.f, a2h = 0.f, a3l = 0.f, a3h = 0.f;

    const unsigned int* Au = (const unsigned int*)A;

    int j = begin;
    for (; j + 4 <= end; j += 4) {
        uint2 p0 = sorted_pe[j + 0];
        uint2 p1 = sorted_pe[j + 1];
        uint2 p2 = sorted_pe[j + 2];
        uint2 p3 = sorted_pe[j + 3];
        int s0 = p0.x & 0xFFFFF;
        int s1 = p1.x & 0xFFFFF;
        int s2 = p2.x & 0xFFFFF;
        int s3 = p3.x & 0xFFFFF;
        unsigned int u0 = Au[(size_t)s0 * 320 + lane];
        unsigned int u1 = Au[(size_t)s1 * 320 + lane];
        unsigned int u2 = Au[(size_t)s2 * 320 + lane];
        unsigned int u3 = Au[(size_t)s3 * 320 + lane];

        float4 w0 = ((const float4*)w_comp)[p0.x >> 20];
        float4 w1 = ((const float4*)w_comp)[p1.x >> 20];
        float4 w2 = ((const float4*)w_comp)[p2.x >> 20];
        float4 w3 = ((const float4*)w_comp)[p3.x >> 20];
        float n0 = __uint_as_float(p0.y), n1 = __uint_as_float(p1.y);
        float n2 = __uint_as_float(p2.y), n3 = __uint_as_float(p3.y);

        float lo, hi;
        lo = __uint_as_float(u0 << 16); hi = __uint_as_float(u0 & 0xffff0000u);
        a0l += (w0.x * n0) * lo; a0h += (w0.x * n0) * hi;
        a1l += (w0.y * n0) * lo; a1h += (w0.y * n0) * hi;
        a2l += (w0.z * n0) * lo; a2h += (w0.z * n0) * hi;
        a3l += (w0.w * n0) * lo; a3h += (w0.w * n0) * hi;
        lo = __uint_as_float(u1 << 16); hi = __uint_as_float(u1 & 0xffff0000u);
        a0l += (w1.x * n1) * lo; a0h += (w1.x * n1) * hi;
        a1l += (w1.y * n1) * lo; a1h += (w1.y * n1) * hi;
        a2l += (w1.z * n1) * lo; a2h += (w1.z * n1) * hi;
        a3l += (w1.w * n1) * lo; a3h += (w1.w * n1) * hi;
        lo = __uint_as_float(u2 << 16); hi = __uint_as_float(u2 & 0xffff0000u);
        a0l += (w2.x * n2) * lo; a0h += (w2.x * n2) * hi;
        a1l += (w2.y * n2) * lo; a1h += (w2.y * n2) * hi;
        a2l += (w2.z * n2) * lo; a2h += (w2.z * n2) * hi;
        a3l += (w2.w * n2) * lo; a3h += (w2.w * n2) * hi;
        lo = __uint_as_float(u3 << 16); hi = __uint_as_float(u3 & 0xffff0000u);
        a0l += (w3.x * n3) * lo; a0h += (w3.x * n3) * hi;
        a1l += (w3.y * n3) * lo; a1h += (w3.y * n3) * hi;
        a2l += (w3.z * n3) * lo; a2h += (w3.z * n3) * hi;
        a3l += (w3.w * n3) * lo; a3h += (w3.w * n3) * hi;
    }
    for (; j < end; ++j) {
        uint2 p = sorted_pe[j];
        int s = p.x & 0xFFFFF;
        float4 wc = ((const float4*)w_comp)[p.x >> 20];
        float nm = __uint_as_float(p.y);
        unsigned int u = Au[(size_t)s * 320 + lane];
        float lo = __uint_as_float(u << 16);
        float hi = __uint_as_float(u & 0xffff0000u);
        a0l += (wc.x * nm) * lo; a0h += (wc.x * nm) * hi;
        a1l += (wc.y * nm) * lo; a1h += (wc.y * nm) * hi;
        a2l += (wc.z * nm) * lo; a2h += (wc.z * nm) * hi;
        a3l += (wc.w * nm) * lo; a3h += (wc.w * nm) * hi;
    }

    unsigned int* ps = (unsigned int*)(A + (size_t)v * A_COLS + 128);
    ps[0 * 64 + lane] = (unsigned int)f2bf(a0l) | ((unsigned int)f2bf(a0h) << 16);
    ps[1 * 64 + lane] = (unsigned int)f2bf(a1l) | ((unsigned int)f2bf(a1h) << 16);
    ps[2 * 64 + lane] = (unsigned int)f2bf(a2l) | ((unsigned int)f2bf(a2h) << 16);
    ps[3 * 64 + lane] = (unsigned int)f2bf(a3l) | ((unsigned int)f2bf(a3h) << 16);
}

// K5: out = relu(bias + A @ Wstack)   (M=50048, N=128, K=640 bf16 MFMA GEMM)
// Wave = 32 rows x 64 cols; block = 128 rows x 64 cols; grid (391, 2).
__global__ __launch_bounds__(256, 4) void gemm_out(
        const unsigned short* __restrict__ A,
        const unsigned short* __restrict__ wt3,
        const float* __restrict__ bias,
        float* __restrict__ out) {
    int wv = threadIdx.x >> 6;
    int lane = threadIdx.x & 63;
    int n16 = lane & 15;
    int quad = lane >> 4;
    int r0 = (blockIdx.x * 4 + wv) * 32;
    int ch = blockIdx.y;            // column half (0/1)

    const unsigned short* ap0 = A + (size_t)(r0 + n16) * A_COLS + quad * 8;
    const unsigned short* ap1 = ap0 + 16 * A_COLS;
    const unsigned short* bp = wt3 + (size_t)(ch * 4) * 512 + (size_t)lane * 8;

    f32x4 acc[2][4];
#pragma unroll
    for (int rt = 0; rt < 2; ++rt)
#pragma unroll
        for (int ct = 0; ct < 4; ++ct)
            acc[rt][ct] = (f32x4)0.f;

    bf16x8 a_cur[2], b_cur[4];
    a_cur[0] = *(const bf16x8*)ap0;
    a_cur[1] = *(const bf16x8*)ap1;
#pragma unroll
    for (int ct = 0; ct < 4; ++ct)
        b_cur[ct] = *(const bf16x8*)(bp + ct * 512);

#pragma unroll
    for (int ks = 0; ks < 20; ++ks) {
        bf16x8 a_nxt[2], b_nxt[4];
        if (ks < 19) {
            a_nxt[0] = *(const bf16x8*)(ap0 + (ks + 1) * 32);
            a_nxt[1] = *(const bf16x8*)(ap1 + (ks + 1) * 32);
#pragma unroll
            for (int ct = 0; ct < 4; ++ct)
                b_nxt[ct] = *(const bf16x8*)(bp + (ks + 1) * 4096 + ct * 512);
        } else {
            a_nxt[0] = a_cur[0];
            a_nxt[1] = a_cur[1];
#pragma unroll
            for (int ct = 0; ct < 4; ++ct) b_nxt[ct] = b_cur[ct];
        }
#pragma unroll
        for (int ct = 0; ct < 4; ++ct) {
            acc[0][ct] = __builtin_amdgcn_mfma_f32_16x16x32_bf16(a_cur[0], b_cur[ct], acc[0][ct], 0, 0, 0);
            acc[1][ct] = __builtin_amdgcn_mfma_f32_16x16x32_bf16(a_cur[1], b_cur[ct], acc[1][ct], 0, 0, 0);
        }
        a_cur[0] = a_nxt[0];
        a_cur[1] = a_nxt[1];
#pragma unroll
        for (int ct = 0; ct < 4; ++ct) b_cur[ct] = b_nxt[ct];
    }

    // C/D layout: col = lane&15, row = quad*4 + reg
#pragma unroll
    for (int rt = 0; rt < 2; ++rt) {
        int rbase = r0 + rt * 16 + quad * 4;
#pragma unroll
        for (int ct = 0; ct < 4; ++ct) {
            int col = ch * 64 + ct * 16 + n16;
            float bv = bias[col];
#pragma unroll
            for (int rg = 0; rg < 4; ++rg) {
                int r = rbase + rg;
                if (r < N_NODES)
                    out[(size_t)r * H_DIM + col] = fmaxf(acc[rt][ct][rg] + bv, 0.f);
            }
        }
    }
}

extern "C" void kernel_launch(void* const* d_in, const int* in_sizes, int n_in,
                              void* d_out, int out_size, void* d_ws, size_t ws_size,
                              hipStream_t stream) {
    const float* h       = (const float*)d_in[0];
    const float* norm    = (const float*)d_in[1];
    const float* basis_w = (const float*)d_in[2];
    const float* w_comp  = (const float*)d_in[3];
    const float* loop_w  = (const float*)d_in[4];
    const float* bias    = (const float*)d_in[5];
    const int*   src     = (const int*)d_in[6];
    const int*   dst     = (const int*)d_in[7];
    const int*   etype   = (const int*)d_in[8];
    float* out = (float*)d_out;

    // ws layout (bytes):
    char* base = (char*)d_ws;
    unsigned short* wt3       = (unsigned short*)(base + 0);          //    163,840
    unsigned short* A         = (unsigned short*)(base + 163840);     // 64,061,440
    int*            offs      = (int*)(base + 64225280);              //    200,064
    uint2*          pkd       = (uint2*)(base + 64425344);            //  6,400,000
    uint2*          bucketed  = (uint2*)(base + 70825344);            //  6,400,000
    uint2*          sorted_pe = (uint2*)(base + 77225344);            //  6,400,000
    int*            gcnt      = (int*)(base + 83625344);              //    156,800
    int*            blkbase   = (int*)(base + 83782144);              //    156,800
    int*            bstart    = (int*)(base + 83938944);              //        788
    // total ~84 MB

    prep_kernel<<<3130, 256, 0, stream>>>(h, basis_w, loop_w, A, wt3);
    edge_prep<<<EP_BLOCKS, 256, 0, stream>>>(src, dst, etype, norm, pkd, gcnt);
    bucket_scan<<<1, 256, 0, stream>>>(gcnt, blkbase, bstart, offs);
    binscatter<<<EP_BLOCKS, 256, 0, stream>>>(pkd, blkbase, bucketed);
    bucket_sort<<<N_RANGES, 256, 0, stream>>>(bstart, bucketed, sorted_pe, offs);
    aggregate_kernel<<<12500, 256, 0, stream>>>(offs, sorted_pe, w_comp, A);
    gemm_out<<<dim3(391, 2), 256, 0, stream>>>(A, wt3, bias, out);
}

// Round 10
// 212.687 us; speedup vs baseline: 1.5869x; 1.0185x over previous
//
#include <hip/hip_runtime.h>
#include <hip/hip_bf16.h>
#include <stdint.h>

#define N_NODES 50000
#define N_EDGES 800000
#define H_DIM 128
#define N_REL 40
#define N_BASES 4
#define A_COLS 640           // [hbf(128) | S(512)] unified per-node row
#define N_RANGES 196         // node ranges of 256 (dst >> 8)
#define EP_BLOCKS 200        // edge chunks of 4000
#define EDGES_PER_BLK 4000
#define STAGE_CAP 5120       // LDS staging capacity for bucket_sort

typedef __attribute__((ext_vector_type(8))) short bf16x8;
typedef __attribute__((ext_vector_type(4))) float f32x4;

// round-to-nearest-even f32 -> bf16 bits
__device__ __forceinline__ unsigned short f2bf(float f) {
    unsigned int u = __float_as_uint(f);
    unsigned int r = u + 0x7fffu + ((u >> 16) & 1u);
    return (unsigned short)(r >> 16);
}

// ---------------------------------------------------------------------------
// K0 "prep" (fused): blocks 0..3124   -> cast h into A[:,0:128] (bf16)
//                    blocks 3125..3129 -> repack weights into frag-major wt3
//                    blocks 3130..3329 -> edge pack (pkd) + per-(bucket,block)
//                                         histogram (LDS only, no dev atomics)
// pkd[e] = { src | etype<<20 , dst | nbf<<17 }  (nbf = bf16 of norm >= 0)
__global__ __launch_bounds__(256) void prep_kernel(
        const float* __restrict__ h,
        const float* __restrict__ basis_w, const float* __restrict__ loop_w,
        const int* __restrict__ src, const int* __restrict__ dst,
        const int* __restrict__ etype, const float* __restrict__ norm,
        unsigned short* __restrict__ A, unsigned short* __restrict__ wt3,
        uint2* __restrict__ pkd, int* __restrict__ gcnt) {
    int bid = blockIdx.x;
    if (bid < 3125) {
        int t = bid * 256 + threadIdx.x;        // [0, 800000)
        int row = t >> 4;
        int cb = (t & 15) * 8;
        const float* p = h + (size_t)row * 128 + cb;
        float4 a0 = ((const float4*)p)[0];
        float4 a1 = ((const float4*)p)[1];
        bf16x8 o;
        o[0] = (short)f2bf(a0.x); o[1] = (short)f2bf(a0.y);
        o[2] = (short)f2bf(a0.z); o[3] = (short)f2bf(a0.w);
        o[4] = (short)f2bf(a1.x); o[5] = (short)f2bf(a1.y);
        o[6] = (short)f2bf(a1.z); o[7] = (short)f2bf(a1.w);
        *(bf16x8*)(A + (size_t)row * A_COLS + cb) = o;
    } else if (bid < 3130) {
        int mat = bid - 3125;                   // 0..3 basis, 4 loop
        const float* srcm = (mat < 4) ? (basis_w + mat * 16384) : loop_w;
        int koff = (mat < 4) ? (128 + mat * 128) : 0;
        int t = threadIdx.x;
#pragma unroll
        for (int i = 0; i < 16; ++i) {
            int f = t + i * 256;                // [0,4096) float4 index
            int k = f >> 5;
            int j4 = (f & 31) * 4;
            float4 v = ((const float4*)srcm)[f];
            int kg = koff + k;
            int ks = kg >> 5;
            int quad = (kg >> 3) & 3;
            int jj = kg & 7;
            float vv[4] = {v.x, v.y, v.z, v.w};
#pragma unroll
            for (int d = 0; d < 4; ++d) {
                int j = j4 + d;
                int cg = j >> 4;
                int n16 = j & 15;
                wt3[(size_t)((ks * 8 + cg) * 64 + quad * 16 + n16) * 8 + jj] =
                    f2bf(vv[d]);
            }
        }
    } else {
        __shared__ int lhist[N_RANGES];
        int blk = bid - 3130;                   // 0..199
        int t = threadIdx.x;
        if (t < N_RANGES) lhist[t] = 0;
        __syncthreads();
        int e0 = blk * EDGES_PER_BLK;
        for (int i = t; i < EDGES_PER_BLK; i += 256) {
            int e = e0 + i;
            int d = dst[e];
            unsigned int nbf = f2bf(norm[e]);   // <= 0x7FFF (norm >= 0)
            pkd[e] = make_uint2((unsigned)src[e] | ((unsigned)etype[e] << 20),
                                (unsigned)d | (nbf << 17));
            atomicAdd(&lhist[d >> 8], 1);
        }
        __syncthreads();
        if (t < N_RANGES) gcnt[t * EP_BLOCKS + blk] = lhist[t];
    }
}

// K1: single block. Thread r: (a) sum gcnt row -> bucket total, (b) shfl
// exclusive scan across 196 buckets -> bstart, (c) walk row emitting blkbase.
__global__ __launch_bounds__(256) void bucket_scan(
        const int* __restrict__ gcnt, int* __restrict__ blkbase,
        int* __restrict__ bstart, int* __restrict__ offs) {
    __shared__ int wsum[4];
    int t = threadIdx.x, lane = t & 63, w = t >> 6;
    int tot = 0;
    if (t < N_RANGES) {
        const int* row = gcnt + t * EP_BLOCKS;
#pragma unroll 8
        for (int b = 0; b < EP_BLOCKS; ++b) tot += row[b];
    }
    int v = tot;
#pragma unroll
    for (int d = 1; d < 64; d <<= 1) {
        int y = __shfl_up(v, d);
        if (lane >= d) v += y;
    }
    if (lane == 63) wsum[w] = v;
    __syncthreads();
    int wpre = 0;
    if (w > 0) wpre += wsum[0];
    if (w > 1) wpre += wsum[1];
    if (w > 2) wpre += wsum[2];
    int excl = wpre + v - tot;
    if (t < N_RANGES) bstart[t] = excl;
    if (t == N_RANGES - 1) {
        bstart[N_RANGES] = wpre + v;            // = N_EDGES
        offs[N_NODES] = wpre + v;
    }
    if (t < N_RANGES) {
        int base = excl;
        const int* row = gcnt + t * EP_BLOCKS;
        int* brow = blkbase + t * EP_BLOCKS;
        for (int b = 0; b < EP_BLOCKS; ++b) { brow[b] = base; base += row[b]; }
    }
}

// K2: binscatter. Block b places its 4000 edges into bucket-grouped order.
// Each (block,bucket) chunk (~20 edges, 160 B) is contiguous -> ~1x write amp.
__global__ __launch_bounds__(256) void binscatter(
        const uint2* __restrict__ pkd, const int* __restrict__ blkbase,
        uint2* __restrict__ bucketed) {
    __shared__ int lcur[N_RANGES];
    int t = threadIdx.x;
    if (t < N_RANGES) lcur[t] = blkbase[t * EP_BLOCKS + blockIdx.x];
    __syncthreads();
    int e0 = blockIdx.x * EDGES_PER_BLK;
    for (int i = t; i < EDGES_PER_BLK; i += 256) {
        uint2 p = pkd[e0 + i];
        int r = (p.y & 0x1FFFF) >> 8;
        int pos = atomicAdd(&lcur[r], 1);
        bucketed[pos] = p;
    }
}

// K3: bucket_sort. One block per bucket. Pass 1: LDS per-dst histogram ->
// 256-wide LDS scan -> per-dst offsets (offs[node] written coalesced).
// Pass 2: place edges into LDS stage by exact sorted position, then stream
// the region out with fully-coalesced writes. Single-writer output region.
__global__ __launch_bounds__(256) void bucket_sort(
        const int* __restrict__ bstart, const uint2* __restrict__ bucketed,
        uint2* __restrict__ sorted_pe, int* __restrict__ offs) {
    __shared__ int hist[256];
    __shared__ int cur[256];
    __shared__ int wsum[4];
    __shared__ uint2 stage[STAGE_CAP];
    int r = blockIdx.x;
    int t = threadIdx.x, lane = t & 63, w = t >> 6;
    int begin = bstart[r];
    int end = bstart[r + 1];
    int n = end - begin;
    hist[t] = 0;
    __syncthreads();
    for (int i = begin + t; i < end; i += 256)
        atomicAdd(&hist[bucketed[i].y & 255], 1);
    __syncthreads();
    int x = hist[t];
    int v = x;
#pragma unroll
    for (int d = 1; d < 64; d <<= 1) {
        int y = __shfl_up(v, d);
        if (lane >= d) v += y;
    }
    if (lane == 63) wsum[w] = v;
    __syncthreads();
    int wpre = 0;
    if (w > 0) wpre += wsum[0];
    if (w > 1) wpre += wsum[1];
    if (w > 2) wpre += wsum[2];
    int excl_rel = wpre + v - x;                // position within the region
    int node = r * 256 + t;
    if (node < N_NODES) offs[node] = begin + excl_rel;
    cur[t] = excl_rel;
    __syncthreads();
    if (n <= STAGE_CAP) {
        for (int i = begin + t; i < end; i += 256) {
            uint2 p = bucketed[i];
            int pos = atomicAdd(&cur[p.y & 255], 1);
            stage[pos] = make_uint2(p.x, (p.y >> 17) << 16);
        }
        __syncthreads();
        for (int i = t; i < n; i += 256)
            sorted_pe[begin + i] = stage[i];
    } else {                                    // pathological fallback
        for (int i = begin + t; i < end; i += 256) {
            uint2 p = bucketed[i];
            int pos = atomicAdd(&cur[p.y & 255], 1);
            sorted_pe[begin + pos] = make_uint2(p.x, (p.y >> 17) << 16);
        }
    }
}

// K4: per-node aggregation, no atomics. One wave per node; edge metadata is
// wave-uniform -> scalar loads (8-wide batches); gather is one 256B row per
// edge (4B/lane), 8 outstanding. A[v][128+b*128+c] = sum cf[b]*A[src][c].
__global__ __launch_bounds__(256) void aggregate_kernel(
        const int* __restrict__ offs, const uint2* __restrict__ sorted_pe,
        const float* __restrict__ w_comp,
        unsigned short* __restrict__ A) {
    int v = __builtin_amdgcn_readfirstlane(blockIdx.x * 4 + (threadIdx.x >> 6));
    if (v >= N_NODES) return;
    int lane = threadIdx.x & 63;
    int begin = offs[v];
    int end = offs[v + 1];

    float a0l = 0.f, a0h = 0.f, a1l = 0.f, a1h = 0.f;
    float a2l = 0.f, a2h = 0.f, a3l = 0.f, a3h = 0.f;

    const unsigned int* Au = (const unsigned int*)A;

    int j = begin;
    for (; j + 8 <= end; j += 8) {
        uint2 p[8];
        unsigned int u[8];
#pragma unroll
        for (int q = 0; q < 8; ++q) p[q] = sorted_pe[j + q];
#pragma unroll
        for (int q = 0; q < 8; ++q)
            u[q] = Au[(size_t)(p[q].x & 0xFFFFF) * 320 + lane];
#pragma unroll
        for (int q = 0; q < 8; ++q) {
            float4 wc = ((const float4*)w_comp)[p[q].x >> 20];
            float nm = __uint_as_float(p[q].y);
            float lo = __uint_as_float(u[q] << 16);
            float hi = __uint_as_float(u[q] & 0xffff0000u);
            a0l += (wc.x * nm) * lo; a0h += (wc.x * nm) * hi;
            a1l += (wc.y * nm) * lo; a1h += (wc.y * nm) * hi;
            a2l += (wc.z * nm) * lo; a2h += (wc.z * nm) * hi;
            a3l += (wc.w * nm) * lo; a3h += (wc.w * nm) * hi;
        }
    }
    for (; j < end; ++j) {
        uint2 p = sorted_pe[j];
        int s = p.x & 0xFFFFF;
        float4 wc = ((const float4*)w_comp)[p.x >> 20];
        float nm = __uint_as_float(p.y);
        unsigned int u = Au[(size_t)s * 320 + lane];
        float lo = __uint_as_float(u << 16);
        float hi = __uint_as_float(u & 0xffff0000u);
        a0l += (wc.x * nm) * lo; a0h += (wc.x * nm) * hi;
        a1l += (wc.y * nm) * lo; a1h += (wc.y * nm) * hi;
        a2l += (wc.z * nm) * lo; a2h += (wc.z * nm) * hi;
        a3l += (wc.w * nm) * lo; a3h += (wc.w * nm) * hi;
    }

    unsigned int* ps = (unsigned int*)(A + (size_t)v * A_COLS + 128);
    ps[0 * 64 + lane] = (unsigned int)f2bf(a0l) | ((unsigned int)f2bf(a0h) << 16);
    ps[1 * 64 + lane] = (unsigned int)f2bf(a1l) | ((unsigned int)f2bf(a1h) << 16);
    ps[2 * 64 + lane] = (unsigned int)f2bf(a2l) | ((unsigned int)f2bf(a2h) << 16);
    ps[3 * 64 + lane] = (unsigned int)f2bf(a3l) | ((unsigned int)f2bf(a3h) << 16);
}

// K5: out = relu(bias + A @ Wstack)   (M=50048, N=128, K=640 bf16 MFMA GEMM)
// Wave = 32 rows x 64 cols; block = 128 rows x 64 cols; grid (391, 2).
__global__ __launch_bounds__(256, 4) void gemm_out(
        const unsigned short* __restrict__ A,
        const unsigned short* __restrict__ wt3,
        const float* __restrict__ bias,
        float* __restrict__ out) {
    int wv = threadIdx.x >> 6;
    int lane = threadIdx.x & 63;
    int n16 = lane & 15;
    int quad = lane >> 4;
    int r0 = (blockIdx.x * 4 + wv) * 32;
    int ch = blockIdx.y;            // column half (0/1)

    const unsigned short* ap0 = A + (size_t)(r0 + n16) * A_COLS + quad * 8;
    const unsigned short* ap1 = ap0 + 16 * A_COLS;
    const unsigned short* bp = wt3 + (size_t)(ch * 4) * 512 + (size_t)lane * 8;

    f32x4 acc[2][4];
#pragma unroll
    for (int rt = 0; rt < 2; ++rt)
#pragma unroll
        for (int ct = 0; ct < 4; ++ct)
            acc[rt][ct] = (f32x4)0.f;

    bf16x8 a_cur[2], b_cur[4];
    a_cur[0] = *(const bf16x8*)ap0;
    a_cur[1] = *(const bf16x8*)ap1;
#pragma unroll
    for (int ct = 0; ct < 4; ++ct)
        b_cur[ct] = *(const bf16x8*)(bp + ct * 512);

#pragma unroll
    for (int ks = 0; ks < 20; ++ks) {
        bf16x8 a_nxt[2], b_nxt[4];
        if (ks < 19) {
            a_nxt[0] = *(const bf16x8*)(ap0 + (ks + 1) * 32);
            a_nxt[1] = *(const bf16x8*)(ap1 + (ks + 1) * 32);
#pragma unroll
            for (int ct = 0; ct < 4; ++ct)
                b_nxt[ct] = *(const bf16x8*)(bp + (ks + 1) * 4096 + ct * 512);
        } else {
            a_nxt[0] = a_cur[0];
            a_nxt[1] = a_cur[1];
#pragma unroll
            for (int ct = 0; ct < 4; ++ct) b_nxt[ct] = b_cur[ct];
        }
#pragma unroll
        for (int ct = 0; ct < 4; ++ct) {
            acc[0][ct] = __builtin_amdgcn_mfma_f32_16x16x32_bf16(a_cur[0], b_cur[ct], acc[0][ct], 0, 0, 0);
            acc[1][ct] = __builtin_amdgcn_mfma_f32_16x16x32_bf16(a_cur[1], b_cur[ct], acc[1][ct], 0, 0, 0);
        }
        a_cur[0] = a_nxt[0];
        a_cur[1] = a_nxt[1];
#pragma unroll
        for (int ct = 0; ct < 4; ++ct) b_cur[ct] = b_nxt[ct];
    }

    // C/D layout: col = lane&15, row = quad*4 + reg
#pragma unroll
    for (int rt = 0; rt < 2; ++rt) {
        int rbase = r0 + rt * 16 + quad * 4;
#pragma unroll
        for (int ct = 0; ct < 4; ++ct) {
            int col = ch * 64 + ct * 16 + n16;
            float bv = bias[col];
#pragma unroll
            for (int rg = 0; rg < 4; ++rg) {
                int r = rbase + rg;
                if (r < N_NODES)
                    out[(size_t)r * H_DIM + col] = fmaxf(acc[rt][ct][rg] + bv, 0.f);
            }
        }
    }
}

extern "C" void kernel_launch(void* const* d_in, const int* in_sizes, int n_in,
                              void* d_out, int out_size, void* d_ws, size_t ws_size,
                              hipStream_t stream) {
    const float* h       = (const float*)d_in[0];
    const float* norm    = (const float*)d_in[1];
    const float* basis_w = (const float*)d_in[2];
    const float* w_comp  = (const float*)d_in[3];
    const float* loop_w  = (const float*)d_in[4];
    const float* bias    = (const float*)d_in[5];
    const int*   src     = (const int*)d_in[6];
    const int*   dst     = (const int*)d_in[7];
    const int*   etype   = (const int*)d_in[8];
    float* out = (float*)d_out;

    // ws layout (bytes):
    char* base = (char*)d_ws;
    unsigned short* wt3       = (unsigned short*)(base + 0);          //    163,840
    unsigned short* A         = (unsigned short*)(base + 163840);     // 64,061,440
    int*            offs      = (int*)(base + 64225280);              //    200,064
    uint2*          pkd       = (uint2*)(base + 64425344);            //  6,400,000
    uint2*          bucketed  = (uint2*)(base + 70825344);            //  6,400,000
    uint2*          sorted_pe = (uint2*)(base + 77225344);            //  6,400,000
    int*            gcnt      = (int*)(base + 83625344);              //    156,800
    int*            blkbase   = (int*)(base + 83782144);              //    156,800
    int*            bstart    = (int*)(base + 83938944);              //        788
    // total ~84 MB

    prep_kernel<<<3330, 256, 0, stream>>>(h, basis_w, loop_w,
                                          src, dst, etype, norm,
                                          A, wt3, pkd, gcnt);
    bucket_scan<<<1, 256, 0, stream>>>(gcnt, blkbase, bstart, offs);
    binscatter<<<EP_BLOCKS, 256, 0, stream>>>(pkd, blkbase, bucketed);
    bucket_sort<<<N_RANGES, 256, 0, stream>>>(bstart, bucketed, sorted_pe, offs);
    aggregate_kernel<<<12500, 256, 0, stream>>>(offs, sorted_pe, w_comp, A);
    gemm_out<<<dim3(391, 2), 256, 0, stream>>>(A, wt3, bias, out);
}

// Round 11
// 198.714 us; speedup vs baseline: 1.6985x; 1.0703x over previous
//
#include <hip/hip_runtime.h>
#include <hip/hip_bf16.h>
#include <stdint.h>

#define N_NODES 50000
#define N_EDGES 800000
#define H_DIM 128
#define N_REL 40
#define N_BASES 4
#define A_COLS 640           // [hbf(128) | S(512)] unified per-node row
#define N_RANGES 196         // node ranges of 256 (dst >> 8)
#define EP_BLOCKS 200        // edge chunks of 4000
#define EDGES_PER_BLK 4000
#define STAGE_CAP 5120       // LDS staging capacity for bucket_sort

typedef __attribute__((ext_vector_type(8))) short bf16x8;
typedef __attribute__((ext_vector_type(4))) float f32x4;

// round-to-nearest-even f32 -> bf16 bits
__device__ __forceinline__ unsigned short f2bf(float f) {
    unsigned int u = __float_as_uint(f);
    unsigned int r = u + 0x7fffu + ((u >> 16) & 1u);
    return (unsigned short)(r >> 16);
}

// ---------------------------------------------------------------------------
// K0 "prep" (fused): blocks 0..3124   -> cast h into A[:,0:128] (bf16)
//                    blocks 3125..3129 -> repack weights into frag-major wt3
//                    blocks 3130..3329 -> edge pack (pkd) + per-(bucket,block)
//                                         histogram (LDS only, no dev atomics)
// pkd[e] = { src | etype<<20 , dst | nbf<<17 }  (nbf = bf16 of norm >= 0)
__global__ __launch_bounds__(256) void prep_kernel(
        const float* __restrict__ h,
        const float* __restrict__ basis_w, const float* __restrict__ loop_w,
        const int* __restrict__ src, const int* __restrict__ dst,
        const int* __restrict__ etype, const float* __restrict__ norm,
        unsigned short* __restrict__ A, unsigned short* __restrict__ wt3,
        uint2* __restrict__ pkd, int* __restrict__ gcnt) {
    int bid = blockIdx.x;
    if (bid < 3125) {
        int t = bid * 256 + threadIdx.x;        // [0, 800000)
        int row = t >> 4;
        int cb = (t & 15) * 8;
        const float* p = h + (size_t)row * 128 + cb;
        float4 a0 = ((const float4*)p)[0];
        float4 a1 = ((const float4*)p)[1];
        bf16x8 o;
        o[0] = (short)f2bf(a0.x); o[1] = (short)f2bf(a0.y);
        o[2] = (short)f2bf(a0.z); o[3] = (short)f2bf(a0.w);
        o[4] = (short)f2bf(a1.x); o[5] = (short)f2bf(a1.y);
        o[6] = (short)f2bf(a1.z); o[7] = (short)f2bf(a1.w);
        *(bf16x8*)(A + (size_t)row * A_COLS + cb) = o;
    } else if (bid < 3130) {
        int mat = bid - 3125;                   // 0..3 basis, 4 loop
        const float* srcm = (mat < 4) ? (basis_w + mat * 16384) : loop_w;
        int koff = (mat < 4) ? (128 + mat * 128) : 0;
        int t = threadIdx.x;
#pragma unroll
        for (int i = 0; i < 16; ++i) {
            int f = t + i * 256;                // [0,4096) float4 index
            int k = f >> 5;
            int j4 = (f & 31) * 4;
            float4 v = ((const float4*)srcm)[f];
            int kg = koff + k;
            int ks = kg >> 5;
            int quad = (kg >> 3) & 3;
            int jj = kg & 7;
            float vv[4] = {v.x, v.y, v.z, v.w};
#pragma unroll
            for (int d = 0; d < 4; ++d) {
                int j = j4 + d;
                int cg = j >> 4;
                int n16 = j & 15;
                wt3[(size_t)((ks * 8 + cg) * 64 + quad * 16 + n16) * 8 + jj] =
                    f2bf(vv[d]);
            }
        }
    } else {
        __shared__ int lhist[N_RANGES];
        int blk = bid - 3130;                   // 0..199
        int t = threadIdx.x;
        if (t < N_RANGES) lhist[t] = 0;
        __syncthreads();
        int e0 = blk * EDGES_PER_BLK;
        for (int i = t; i < EDGES_PER_BLK; i += 256) {
            int e = e0 + i;
            int d = dst[e];
            unsigned int nbf = f2bf(norm[e]);   // <= 0x7FFF (norm >= 0)
            pkd[e] = make_uint2((unsigned)src[e] | ((unsigned)etype[e] << 20),
                                (unsigned)d | (nbf << 17));
            atomicAdd(&lhist[d >> 8], 1);
        }
        __syncthreads();
        if (t < N_RANGES) gcnt[t * EP_BLOCKS + blk] = lhist[t];
    }
}

// K1a: parallel per-bucket row scan. Block r: LDS-scan gcnt[r][0..199] ->
// RELATIVE blkbase (bstart added later in binscatter) + bucket total btot[r].
__global__ __launch_bounds__(256) void bucket_scan_a(
        const int* __restrict__ gcnt, int* __restrict__ blkbase,
        int* __restrict__ btot) {
    __shared__ int wsum[4];
    int r = blockIdx.x;
    int t = threadIdx.x, lane = t & 63, w = t >> 6;
    int x = (t < EP_BLOCKS) ? gcnt[r * EP_BLOCKS + t] : 0;
    int v = x;
#pragma unroll
    for (int d = 1; d < 64; d <<= 1) {
        int y = __shfl_up(v, d);
        if (lane >= d) v += y;
    }
    if (lane == 63) wsum[w] = v;
    __syncthreads();
    int wpre = 0;
    if (w > 0) wpre += wsum[0];
    if (w > 1) wpre += wsum[1];
    if (w > 2) wpre += wsum[2];
    if (t < EP_BLOCKS) blkbase[r * EP_BLOCKS + t] = wpre + v - x;
    if (t == 255) btot[r] = wpre + v;
}

// K1b: single tiny block: exclusive scan of 196 bucket totals -> bstart,
// grand total -> bstart[196] and offs[N_NODES].
__global__ __launch_bounds__(256) void bucket_scan_b(
        const int* __restrict__ btot, int* __restrict__ bstart,
        int* __restrict__ offs) {
    __shared__ int wsum[4];
    int t = threadIdx.x, lane = t & 63, w = t >> 6;
    int x = (t < N_RANGES) ? btot[t] : 0;
    int v = x;
#pragma unroll
    for (int d = 1; d < 64; d <<= 1) {
        int y = __shfl_up(v, d);
        if (lane >= d) v += y;
    }
    if (lane == 63) wsum[w] = v;
    __syncthreads();
    int wpre = 0;
    if (w > 0) wpre += wsum[0];
    if (w > 1) wpre += wsum[1];
    if (w > 2) wpre += wsum[2];
    if (t < N_RANGES) bstart[t] = wpre + v - x;
    if (t == 255) {
        bstart[N_RANGES] = wpre + v;            // = N_EDGES
        offs[N_NODES] = wpre + v;
    }
}

// K2: binscatter. Block b places its 4000 edges into bucket-grouped order.
// Cursor init = bstart[r] + relative blkbase. Each (block,bucket) chunk
// (~20 edges, 160 B) is contiguous -> ~1x write amp.
__global__ __launch_bounds__(256) void binscatter(
        const uint2* __restrict__ pkd, const int* __restrict__ blkbase,
        const int* __restrict__ bstart, uint2* __restrict__ bucketed) {
    __shared__ int lcur[N_RANGES];
    int t = threadIdx.x;
    if (t < N_RANGES)
        lcur[t] = bstart[t] + blkbase[t * EP_BLOCKS + blockIdx.x];
    __syncthreads();
    int e0 = blockIdx.x * EDGES_PER_BLK;
    for (int i = t; i < EDGES_PER_BLK; i += 256) {
        uint2 p = pkd[e0 + i];
        int r = (p.y & 0x1FFFF) >> 8;
        int pos = atomicAdd(&lcur[r], 1);
        bucketed[pos] = p;
    }
}

// K3: bucket_sort. One block per bucket. Pass 1: LDS per-dst histogram ->
// 256-wide LDS scan -> per-dst offsets (offs[node] written coalesced).
// Pass 2: place edges into LDS stage by exact sorted position, then stream
// the region out with fully-coalesced writes. Single-writer output region.
__global__ __launch_bounds__(256) void bucket_sort(
        const int* __restrict__ bstart, const uint2* __restrict__ bucketed,
        uint2* __restrict__ sorted_pe, int* __restrict__ offs) {
    __shared__ int hist[256];
    __shared__ int cur[256];
    __shared__ int wsum[4];
    __shared__ uint2 stage[STAGE_CAP];
    int r = blockIdx.x;
    int t = threadIdx.x, lane = t & 63, w = t >> 6;
    int begin = bstart[r];
    int end = bstart[r + 1];
    int n = end - begin;
    hist[t] = 0;
    __syncthreads();
    for (int i = begin + t; i < end; i += 256)
        atomicAdd(&hist[bucketed[i].y & 255], 1);
    __syncthreads();
    int x = hist[t];
    int v = x;
#pragma unroll
    for (int d = 1; d < 64; d <<= 1) {
        int y = __shfl_up(v, d);
        if (lane >= d) v += y;
    }
    if (lane == 63) wsum[w] = v;
    __syncthreads();
    int wpre = 0;
    if (w > 0) wpre += wsum[0];
    if (w > 1) wpre += wsum[1];
    if (w > 2) wpre += wsum[2];
    int excl_rel = wpre + v - x;                // position within the region
    int node = r * 256 + t;
    if (node < N_NODES) offs[node] = begin + excl_rel;
    cur[t] = excl_rel;
    __syncthreads();
    if (n <= STAGE_CAP) {
        for (int i = begin + t; i < end; i += 256) {
            uint2 p = bucketed[i];
            int pos = atomicAdd(&cur[p.y & 255], 1);
            stage[pos] = make_uint2(p.x, (p.y >> 17) << 16);
        }
        __syncthreads();
        for (int i = t; i < n; i += 256)
            sorted_pe[begin + i] = stage[i];
    } else {                                    // pathological fallback
        for (int i = begin + t; i < end; i += 256) {
            uint2 p = bucketed[i];
            int pos = atomicAdd(&cur[p.y & 255], 1);
            sorted_pe[begin + pos] = make_uint2(p.x, (p.y >> 17) << 16);
        }
    }
}

// K4: per-node aggregation, no atomics. One wave per node; edge metadata is
// wave-uniform -> scalar loads (8-wide batches); gather is one 256B row per
// edge (4B/lane), 8 outstanding. A[v][128+b*128+c] = sum cf[b]*A[src][c].
__global__ __launch_bounds__(256) void aggregate_kernel(
        const int* __restrict__ offs, const uint2* __restrict__ sorted_pe,
        const float* __restrict__ w_comp,
        unsigned short* __restrict__ A) {
    int v = __builtin_amdgcn_readfirstlane(blockIdx.x * 4 + (threadIdx.x >> 6));
    if (v >= N_NODES) return;
    int lane = threadIdx.x & 63;
    int begin = offs[v];
    int end = offs[v + 1];

    float a0l = 0.f, a0h = 0.f, a1l = 0.f, a1h = 0.f;
    float a2l = 0.f, a2h = 0.f, a3l = 0.f, a3h = 0.f;

    const unsigned int* Au = (const unsigned int*)A;

    int j = begin;
    for (; j + 8 <= end; j += 8) {
        uint2 p[8];
        unsigned int u[8];
#pragma unroll
        for (int q = 0; q < 8; ++q) p[q] = sorted_pe[j + q];
#pragma unroll
        for (int q = 0; q < 8; ++q)
            u[q] = Au[(size_t)(p[q].x & 0xFFFFF) * 320 + lane];
#pragma unroll
        for (int q = 0; q < 8; ++q) {
            float4 wc = ((const float4*)w_comp)[p[q].x >> 20];
            float nm = __uint_as_float(p[q].y);
            float lo = __uint_as_float(u[q] << 16);
            float hi = __uint_as_float(u[q] & 0xffff0000u);
            a0l += (wc.x * nm) * lo; a0h += (wc.x * nm) * hi;
            a1l += (wc.y * nm) * lo; a1h += (wc.y * nm) * hi;
            a2l += (wc.z * nm) * lo; a2h += (wc.z * nm) * hi;
            a3l += (wc.w * nm) * lo; a3h += (wc.w * nm) * hi;
        }
    }
    for (; j < end; ++j) {
        uint2 p = sorted_pe[j];
        int s = p.x & 0xFFFFF;
        float4 wc = ((const float4*)w_comp)[p.x >> 20];
        float nm = __uint_as_float(p.y);
        unsigned int u = Au[(size_t)s * 320 + lane];
        float lo = __uint_as_float(u << 16);
        float hi = __uint_as_float(u & 0xffff0000u);
        a0l += (wc.x * nm) * lo; a0h += (wc.x * nm) * hi;
        a1l += (wc.y * nm) * lo; a1h += (wc.y * nm) * hi;
        a2l += (wc.z * nm) * lo; a2h += (wc.z * nm) * hi;
        a3l += (wc.w * nm) * lo; a3h += (wc.w * nm) * hi;
    }

    unsigned int* ps = (unsigned int*)(A + (size_t)v * A_COLS + 128);
    ps[0 * 64 + lane] = (unsigned int)f2bf(a0l) | ((unsigned int)f2bf(a0h) << 16);
    ps[1 * 64 + lane] = (unsigned int)f2bf(a1l) | ((unsigned int)f2bf(a1h) << 16);
    ps[2 * 64 + lane] = (unsigned int)f2bf(a2l) | ((unsigned int)f2bf(a2h) << 16);
    ps[3 * 64 + lane] = (unsigned int)f2bf(a3l) | ((unsigned int)f2bf(a3h) << 16);
}

// K5: out = relu(bias + A @ Wstack)   (M=50048, N=128, K=640 bf16 MFMA GEMM)
// v3: wave = 32 rows x ALL 128 cols (ct=8) -> A is streamed exactly once
// (64 MB instead of 128). grid = 391, ~6 waves/CU; B frag-major coalesced,
// 2-deep register prefetch; ~16 MFMA per 10 loads hides latency per-wave.
__global__ __launch_bounds__(256, 2) void gemm_out(
        const unsigned short* __restrict__ A,
        const unsigned short* __restrict__ wt3,
        const float* __restrict__ bias,
        float* __restrict__ out) {
    int wv = threadIdx.x >> 6;
    int lane = threadIdx.x & 63;
    int n16 = lane & 15;
    int quad = lane >> 4;
    int r0 = (blockIdx.x * 4 + wv) * 32;

    const unsigned short* ap0 = A + (size_t)(r0 + n16) * A_COLS + quad * 8;
    const unsigned short* ap1 = ap0 + 16 * A_COLS;
    const unsigned short* bp = wt3 + (size_t)lane * 8;

    f32x4 acc[2][8];
#pragma unroll
    for (int rt = 0; rt < 2; ++rt)
#pragma unroll
        for (int ct = 0; ct < 8; ++ct)
            acc[rt][ct] = (f32x4)0.f;

    bf16x8 a_cur[2], b_cur[8];
    a_cur[0] = *(const bf16x8*)ap0;
    a_cur[1] = *(const bf16x8*)ap1;
#pragma unroll
    for (int ct = 0; ct < 8; ++ct)
        b_cur[ct] = *(const bf16x8*)(bp + ct * 512);

#pragma unroll
    for (int ks = 0; ks < 20; ++ks) {
        bf16x8 a_nxt[2], b_nxt[8];
        if (ks < 19) {
            a_nxt[0] = *(const bf16x8*)(ap0 + (ks + 1) * 32);
            a_nxt[1] = *(const bf16x8*)(ap1 + (ks + 1) * 32);
#pragma unroll
            for (int ct = 0; ct < 8; ++ct)
                b_nxt[ct] = *(const bf16x8*)(bp + (ks + 1) * 4096 + ct * 512);
        } else {
            a_nxt[0] = a_cur[0];
            a_nxt[1] = a_cur[1];
#pragma unroll
            for (int ct = 0; ct < 8; ++ct) b_nxt[ct] = b_cur[ct];
        }
#pragma unroll
        for (int ct = 0; ct < 8; ++ct) {
            acc[0][ct] = __builtin_amdgcn_mfma_f32_16x16x32_bf16(a_cur[0], b_cur[ct], acc[0][ct], 0, 0, 0);
            acc[1][ct] = __builtin_amdgcn_mfma_f32_16x16x32_bf16(a_cur[1], b_cur[ct], acc[1][ct], 0, 0, 0);
        }
        a_cur[0] = a_nxt[0];
        a_cur[1] = a_nxt[1];
#pragma unroll
        for (int ct = 0; ct < 8; ++ct) b_cur[ct] = b_nxt[ct];
    }

    // C/D layout: col = lane&15, row = quad*4 + reg
#pragma unroll
    for (int rt = 0; rt < 2; ++rt) {
        int rbase = r0 + rt * 16 + quad * 4;
#pragma unroll
        for (int ct = 0; ct < 8; ++ct) {
            int col = ct * 16 + n16;
            float bv = bias[col];
#pragma unroll
            for (int rg = 0; rg < 4; ++rg) {
                int r = rbase + rg;
                if (r < N_NODES)
                    out[(size_t)r * H_DIM + col] = fmaxf(acc[rt][ct][rg] + bv, 0.f);
            }
        }
    }
}

extern "C" void kernel_launch(void* const* d_in, const int* in_sizes, int n_in,
                              void* d_out, int out_size, void* d_ws, size_t ws_size,
                              hipStream_t stream) {
    const float* h       = (const float*)d_in[0];
    const float* norm    = (const float*)d_in[1];
    const float* basis_w = (const float*)d_in[2];
    const float* w_comp  = (const float*)d_in[3];
    const float* loop_w  = (const float*)d_in[4];
    const float* bias    = (const float*)d_in[5];
    const int*   src     = (const int*)d_in[6];
    const int*   dst     = (const int*)d_in[7];
    const int*   etype   = (const int*)d_in[8];
    float* out = (float*)d_out;

    // ws layout (bytes):
    char* base = (char*)d_ws;
    unsigned short* wt3       = (unsigned short*)(base + 0);          //    163,840
    unsigned short* A         = (unsigned short*)(base + 163840);     // 64,061,440
    int*            offs      = (int*)(base + 64225280);              //    200,064
    uint2*          pkd       = (uint2*)(base + 64425344);            //  6,400,000
    uint2*          bucketed  = (uint2*)(base + 70825344);            //  6,400,000
    uint2*          sorted_pe = (uint2*)(base + 77225344);            //  6,400,000
    int*            gcnt      = (int*)(base + 83625344);              //    156,800
    int*            blkbase   = (int*)(base + 83782144);              //    156,800
    int*            bstart    = (int*)(base + 83938944);              //        788
    int*            btot      = (int*)(base + 83939732);              //        784
    // total ~84 MB

    prep_kernel<<<3330, 256, 0, stream>>>(h, basis_w, loop_w,
                                          src, dst, etype, norm,
                                          A, wt3, pkd, gcnt);
    bucket_scan_a<<<N_RANGES, 256, 0, stream>>>(gcnt, blkbase, btot);
    bucket_scan_b<<<1, 256, 0, stream>>>(btot, bstart, offs);
    binscatter<<<EP_BLOCKS, 256, 0, stream>>>(pkd, blkbase, bstart, bucketed);
    bucket_sort<<<N_RANGES, 256, 0, stream>>>(bstart, bucketed, sorted_pe, offs);
    aggregate_kernel<<<12500, 256, 0, stream>>>(offs, sorted_pe, w_comp, A);
    gemm_out<<<391, 256, 0, stream>>>(A, wt3, bias, out);
}